// Round 1
// baseline (190.200 us; speedup 1.0000x reference)
//
#include <hip/hip_runtime.h>
#include <math.h>

#define NTOK 784
#define DIM 128
#define FFD 512

__device__ __forceinline__ float blockReduceSum128(float v, float* red) {
#pragma unroll
  for (int off = 32; off > 0; off >>= 1) v += __shfl_down(v, off, 64);
  int lane = threadIdx.x & 63;
  int wid = threadIdx.x >> 6;
  if (lane == 0) red[wid] = v;
  __syncthreads();
  float s = red[0] + red[1];
  __syncthreads();
  return s;
}

// LayerNorm over a row gathered from [C, N] layout -> out [N, C]
__global__ void ln_from_chw(const float* __restrict__ x, const float* __restrict__ g,
                            const float* __restrict__ b, float* __restrict__ out) {
  __shared__ float red[2];
  int n = blockIdx.x, c = threadIdx.x;
  float v = x[c * NTOK + n];
  float mean = blockReduceSum128(v, red) * (1.0f / DIM);
  float d = v - mean;
  float var = blockReduceSum128(d * d, red) * (1.0f / DIM);
  out[n * DIM + c] = d * rsqrtf(var + 1e-5f) * g[c] + b[c];
}

// LayerNorm over row-major [N, C]
__global__ void ln_rows(const float* __restrict__ t, const float* __restrict__ g,
                        const float* __restrict__ b, float* __restrict__ out) {
  __shared__ float red[2];
  int n = blockIdx.x, c = threadIdx.x;
  float v = t[n * DIM + c];
  float mean = blockReduceSum128(v, red) * (1.0f / DIM);
  float d = v - mean;
  float var = blockReduceSum128(d * d, red) * (1.0f / DIM);
  out[n * DIM + c] = d * rsqrtf(var + 1e-5f) * g[c] + b[c];
}

// q = sigmoid(xn @ wq^T), ek = exp(xn @ wk^T), ekv = ek * (xn @ wv^T)
__global__ void qkv_kernel(const float* __restrict__ xn, const float* __restrict__ wq,
                           const float* __restrict__ wk, const float* __restrict__ wv,
                           float* __restrict__ q, float* __restrict__ ek,
                           float* __restrict__ ekv) {
  __shared__ float xr[DIM];
  int n = blockIdx.x, d = threadIdx.x;
  xr[d] = xn[n * DIM + d];
  __syncthreads();
  float aq = 0.f, ak = 0.f, av = 0.f;
  const float* wqr = wq + d * DIM;
  const float* wkr = wk + d * DIM;
  const float* wvr = wv + d * DIM;
#pragma unroll 8
  for (int i = 0; i < DIM; ++i) {
    float xv = xr[i];
    aq = fmaf(xv, wqr[i], aq);
    ak = fmaf(xv, wkr[i], ak);
    av = fmaf(xv, wvr[i], av);
  }
  q[n * DIM + d] = 1.0f / (1.0f + expf(-aq));
  float e = expf(ak);
  ek[n * DIM + d] = e;
  ekv[n * DIM + d] = e * av;
}

// W[n][m] = exp(dot(u[n], v[m]))
__global__ void posw_kernel(const float* __restrict__ pu, const float* __restrict__ pv,
                            float* __restrict__ W) {
  __shared__ float ur[DIM];
  int n = blockIdx.x;
  int tid = threadIdx.x;  // 128
  ur[tid] = pu[n * DIM + tid];
  __syncthreads();
  for (int m = tid; m < NTOK; m += 128) {
    const float* vr = pv + m * DIM;
    float acc = 0.f;
#pragma unroll 8
    for (int i = 0; i < DIM; ++i) acc = fmaf(ur[i], vr[i], acc);
    W[n * NTOK + m] = expf(acc);
  }
}

// num = W @ ekv, den = W @ ek, out = q * num/den
__global__ void agg_kernel(const float* __restrict__ W, const float* __restrict__ ek,
                           const float* __restrict__ ekv, const float* __restrict__ q,
                           float* __restrict__ out) {
  __shared__ float wr[NTOK];
  int n = blockIdx.x, d = threadIdx.x;
  for (int m = d; m < NTOK; m += 128) wr[m] = W[n * NTOK + m];
  __syncthreads();
  float num = 0.f, den = 0.f;
  for (int m = 0; m < NTOK; ++m) {
    float w = wr[m];
    num = fmaf(w, ekv[m * DIM + d], num);
    den = fmaf(w, ek[m * DIM + d], den);
  }
  out[n * DIM + d] = q[n * DIM + d] * (num / den);
}

// t2 = attn_out @ wo^T + bo + residual(x in CHW layout)
__global__ void proj_res_kernel(const float* __restrict__ ao, const float* __restrict__ wo,
                                const float* __restrict__ bo, const float* __restrict__ x,
                                float* __restrict__ t2) {
  __shared__ float ar[DIM];
  int n = blockIdx.x, c = threadIdx.x;
  ar[c] = ao[n * DIM + c];
  __syncthreads();
  float acc = bo[c];
  const float* wr = wo + c * DIM;
#pragma unroll 8
  for (int i = 0; i < DIM; ++i) acc = fmaf(ar[i], wr[i], acc);
  t2[n * DIM + c] = acc + x[c * NTOK + n];
}

// ff1 = gelu_exact(fn @ w1^T + b1), [N, FFD], block = 512 threads
__global__ void ff1_kernel(const float* __restrict__ fn, const float* __restrict__ w1,
                           const float* __restrict__ b1, float* __restrict__ ff1) {
  __shared__ float fr[DIM];
  int n = blockIdx.x, f = threadIdx.x;  // 512
  if (f < DIM) fr[f] = fn[n * DIM + f];
  __syncthreads();
  float acc = b1[f];
  const float* wr = w1 + f * DIM;
#pragma unroll 8
  for (int i = 0; i < DIM; ++i) acc = fmaf(fr[i], wr[i], acc);
  float ge = 0.5f * acc * (1.0f + erff(acc * 0.70710678118654752f));
  ff1[n * FFD + f] = ge;
}

// out = (ff1 @ w2^T + b2 + t2) written back to [C, H*W] layout
__global__ void ff2_out_kernel(const float* __restrict__ ff1, const float* __restrict__ w2,
                               const float* __restrict__ b2, const float* __restrict__ t2,
                               float* __restrict__ out) {
  __shared__ float fr[FFD];
  int n = blockIdx.x, c = threadIdx.x;  // 128
  for (int i = c; i < FFD; i += DIM) fr[i] = ff1[n * FFD + i];
  __syncthreads();
  float acc = b2[c];
  const float* wr = w2 + c * FFD;
#pragma unroll 8
  for (int i = 0; i < FFD; ++i) acc = fmaf(fr[i], wr[i], acc);
  out[c * NTOK + n] = t2[n * DIM + c] + acc;
}

extern "C" void kernel_launch(void* const* d_in, const int* in_sizes, int n_in,
                              void* d_out, int out_size, void* d_ws, size_t ws_size,
                              hipStream_t stream) {
  const float* x   = (const float*)d_in[0];
  const float* wq  = (const float*)d_in[1];
  const float* wk  = (const float*)d_in[2];
  const float* wv  = (const float*)d_in[3];
  const float* wo  = (const float*)d_in[4];
  const float* bo  = (const float*)d_in[5];
  const float* pu  = (const float*)d_in[6];
  const float* pv  = (const float*)d_in[7];
  const float* g1  = (const float*)d_in[8];
  const float* b1n = (const float*)d_in[9];
  const float* g2  = (const float*)d_in[10];
  const float* b2n = (const float*)d_in[11];
  const float* w1  = (const float*)d_in[12];
  const float* b1f = (const float*)d_in[13];
  const float* w2  = (const float*)d_in[14];
  const float* b2f = (const float*)d_in[15];
  float* out = (float*)d_out;

  float* ws = (float*)d_ws;
  float* xn  = ws;                  // [784,128]; reused as attn_out
  float* q   = ws + 100352;         // [784,128]
  float* ek  = ws + 200704;         // [784,128]; reused as t2
  float* ekv = ws + 301056;         // [784,128]; reused as fn
  float* W   = ws + 401408;         // [784,784]; reused as ff1 [784,512]

  ln_from_chw<<<NTOK, DIM, 0, stream>>>(x, g1, b1n, xn);
  qkv_kernel<<<NTOK, DIM, 0, stream>>>(xn, wq, wk, wv, q, ek, ekv);
  posw_kernel<<<NTOK, DIM, 0, stream>>>(pu, pv, W);
  agg_kernel<<<NTOK, DIM, 0, stream>>>(W, ek, ekv, q, xn);      // xn := attn_out
  proj_res_kernel<<<NTOK, DIM, 0, stream>>>(xn, wo, bo, x, ek); // ek := t2
  ln_rows<<<NTOK, DIM, 0, stream>>>(ek, g2, b2n, ekv);          // ekv := fn
  ff1_kernel<<<NTOK, FFD, 0, stream>>>(ekv, w1, b1f, W);        // W := ff1
  ff2_out_kernel<<<NTOK, DIM, 0, stream>>>(W, w2, b2f, ek, out);
}

// Round 2
// 102.946 us; speedup vs baseline: 1.8476x; 1.8476x over previous
//
#include <hip/hip_runtime.h>
#include <math.h>

#define NTOK 784
#define DIM 128
#define FFD 512

// ---------------- LayerNorm ----------------
__device__ __forceinline__ float blockReduceSum128(float v, float* red) {
#pragma unroll
  for (int off = 32; off > 0; off >>= 1) v += __shfl_down(v, off, 64);
  int lane = threadIdx.x & 63;
  int wid = threadIdx.x >> 6;
  if (lane == 0) red[wid] = v;
  __syncthreads();
  float s = red[0] + red[1];
  __syncthreads();
  return s;
}

// LN over channel dim, input [C,N] layout; also writes raw transposed xt [N,C]
__global__ void ln_from_chw(const float* __restrict__ x, const float* __restrict__ g,
                            const float* __restrict__ b, float* __restrict__ out,
                            float* __restrict__ xt) {
  __shared__ float red[2];
  int n = blockIdx.x, c = threadIdx.x;
  float v = x[c * NTOK + n];
  xt[n * DIM + c] = v;
  float mean = blockReduceSum128(v, red) * (1.0f / DIM);
  float d = v - mean;
  float var = blockReduceSum128(d * d, red) * (1.0f / DIM);
  out[n * DIM + c] = d * rsqrtf(var + 1e-5f) * g[c] + b[c];
}

__global__ void ln_rows(const float* __restrict__ t, const float* __restrict__ g,
                        const float* __restrict__ b, float* __restrict__ out) {
  __shared__ float red[2];
  int n = blockIdx.x, c = threadIdx.x;
  float v = t[n * DIM + c];
  float mean = blockReduceSum128(v, red) * (1.0f / DIM);
  float d = v - mean;
  float var = blockReduceSum128(d * d, red) * (1.0f / DIM);
  out[n * DIM + c] = d * rsqrtf(var + 1e-5f) * g[c] + b[c];
}

// ---------------- Tiled GEMMs (fp32, TM=TN=64, TK=32) ----------------
// LDS layout is k-major: As[kk][m] so the inner loop does broadcast (a) +
// contiguous float4 (b) reads -> at most 2-way bank aliasing (free).

// q = sigmoid(xn@wq^T), ek = exp(xn@wk^T), vv = xn@wv^T   grid (13, 6), 256 thr
__global__ __launch_bounds__(256) void qkv_gemm(
    const float* __restrict__ xn, const float* __restrict__ wq,
    const float* __restrict__ wk, const float* __restrict__ wv,
    float* __restrict__ q, float* __restrict__ ek, float* __restrict__ vv) {
  __shared__ float As[32][64];
  __shared__ float Bs[32][64];
  int tid = threadIdx.x;
  int m0 = blockIdx.x * 64;
  int ct = blockIdx.y;            // 0..5
  int wsel = ct >> 1;             // 0:q 1:k 2:v
  const float* B = (wsel == 0) ? wq : (wsel == 1) ? wk : wv;
  int n0 = (ct & 1) * 64;         // col offset within 128
  int tx = tid & 15, ty = tid >> 4;
  int r = tid >> 2, kq = (tid & 3) * 8;
  int gm = m0 + r; if (gm > NTOK - 1) gm = NTOK - 1;
  float acc[4][4] = {};
  for (int kt = 0; kt < 4; ++kt) {
    int k0 = kt * 32;
#pragma unroll
    for (int j = 0; j < 8; ++j) As[kq + j][r] = xn[gm * DIM + k0 + kq + j];
#pragma unroll
    for (int j = 0; j < 8; ++j) Bs[kq + j][r] = B[(n0 + r) * DIM + k0 + kq + j];
    __syncthreads();
#pragma unroll
    for (int kk = 0; kk < 32; ++kk) {
      float4 a4 = *(const float4*)&As[kk][ty * 4];
      float4 b4 = *(const float4*)&Bs[kk][tx * 4];
      float av[4] = {a4.x, a4.y, a4.z, a4.w};
      float bv[4] = {b4.x, b4.y, b4.z, b4.w};
#pragma unroll
      for (int i = 0; i < 4; ++i)
#pragma unroll
        for (int j = 0; j < 4; ++j) acc[i][j] = fmaf(av[i], bv[j], acc[i][j]);
    }
    __syncthreads();
  }
  int c0 = n0 + tx * 4;
  float* dst = (wsel == 0) ? q : (wsel == 1) ? ek : vv;
#pragma unroll
  for (int i = 0; i < 4; ++i) {
    int gr = m0 + ty * 4 + i;
    if (gr < NTOK) {
      float4 o;
      if (wsel == 0) {
        o.x = 1.0f / (1.0f + expf(-acc[i][0]));
        o.y = 1.0f / (1.0f + expf(-acc[i][1]));
        o.z = 1.0f / (1.0f + expf(-acc[i][2]));
        o.w = 1.0f / (1.0f + expf(-acc[i][3]));
      } else if (wsel == 1) {
        o.x = expf(acc[i][0]); o.y = expf(acc[i][1]);
        o.z = expf(acc[i][2]); o.w = expf(acc[i][3]);
      } else {
        o.x = acc[i][0]; o.y = acc[i][1]; o.z = acc[i][2]; o.w = acc[i][3];
      }
      *(float4*)&dst[gr * DIM + c0] = o;
    }
  }
}

// W = exp(u @ v^T)   grid (13, 13), 256 thr
__global__ __launch_bounds__(256) void posw_gemm(
    const float* __restrict__ pu, const float* __restrict__ pv, float* __restrict__ W) {
  __shared__ float As[32][64];
  __shared__ float Bs[32][64];
  int tid = threadIdx.x;
  int m0 = blockIdx.x * 64, n0 = blockIdx.y * 64;
  int tx = tid & 15, ty = tid >> 4;
  int r = tid >> 2, kq = (tid & 3) * 8;
  int gm = m0 + r; if (gm > NTOK - 1) gm = NTOK - 1;
  int gn = n0 + r; if (gn > NTOK - 1) gn = NTOK - 1;
  float acc[4][4] = {};
  for (int kt = 0; kt < 4; ++kt) {
    int k0 = kt * 32;
#pragma unroll
    for (int j = 0; j < 8; ++j) As[kq + j][r] = pu[gm * DIM + k0 + kq + j];
#pragma unroll
    for (int j = 0; j < 8; ++j) Bs[kq + j][r] = pv[gn * DIM + k0 + kq + j];
    __syncthreads();
#pragma unroll
    for (int kk = 0; kk < 32; ++kk) {
      float4 a4 = *(const float4*)&As[kk][ty * 4];
      float4 b4 = *(const float4*)&Bs[kk][tx * 4];
      float av[4] = {a4.x, a4.y, a4.z, a4.w};
      float bv[4] = {b4.x, b4.y, b4.z, b4.w};
#pragma unroll
      for (int i = 0; i < 4; ++i)
#pragma unroll
        for (int j = 0; j < 4; ++j) acc[i][j] = fmaf(av[i], bv[j], acc[i][j]);
    }
    __syncthreads();
  }
  int c0 = n0 + tx * 4;
  if (c0 + 3 < NTOK) {
#pragma unroll
    for (int i = 0; i < 4; ++i) {
      int gr = m0 + ty * 4 + i;
      if (gr < NTOK) {
        float4 o = {expf(acc[i][0]), expf(acc[i][1]), expf(acc[i][2]), expf(acc[i][3])};
        *(float4*)&W[gr * NTOK + c0] = o;
      }
    }
  }
}

// num_part/den_part = K-split of W @ [ek*vv | ek]   grid (13, 2, 4), 512 thr
__global__ __launch_bounds__(512) void agg_gemm(
    const float* __restrict__ W, const float* __restrict__ ek,
    const float* __restrict__ vv, float* __restrict__ nump, float* __restrict__ denp) {
  __shared__ float As[32][64];
  __shared__ float Bn[32][64];
  __shared__ float Bd[32][64];
  int tid = threadIdx.x;
  int m0 = blockIdx.x * 64, d0 = blockIdx.y * 64, s = blockIdx.z;
  int tx = tid & 15, ty = tid >> 4;        // ty 0..31: 2 rows x 4 cols per thread
  int ra = tid >> 3, ka = (tid & 7) * 4;   // A staging (transpose)
  int kb = tid >> 4, db = (tid & 15) * 4;  // B staging (direct)
  int gm = m0 + ra; if (gm > NTOK - 1) gm = NTOK - 1;
  float an[2][4] = {}, ad[2][4] = {};
  int ktlo = (s * 25) / 4, kthi = ((s + 1) * 25) / 4;
  for (int kt = ktlo; kt < kthi; ++kt) {
    int k0 = kt * 32;
    if (k0 + 32 <= NTOK) {
      float4 a = *(const float4*)&W[gm * NTOK + k0 + ka];
      As[ka + 0][ra] = a.x; As[ka + 1][ra] = a.y;
      As[ka + 2][ra] = a.z; As[ka + 3][ra] = a.w;
      int gk = k0 + kb;
      float4 e = *(const float4*)&ek[gk * DIM + d0 + db];
      float4 w = *(const float4*)&vv[gk * DIM + d0 + db];
      Bd[kb][db + 0] = e.x; Bd[kb][db + 1] = e.y; Bd[kb][db + 2] = e.z; Bd[kb][db + 3] = e.w;
      Bn[kb][db + 0] = e.x * w.x; Bn[kb][db + 1] = e.y * w.y;
      Bn[kb][db + 2] = e.z * w.z; Bn[kb][db + 3] = e.w * w.w;
    } else {
#pragma unroll
      for (int j = 0; j < 4; ++j) {
        int gk = k0 + ka + j;
        As[ka + j][ra] = (gk < NTOK) ? W[gm * NTOK + gk] : 0.f;
      }
      int gk = k0 + kb;
      if (gk < NTOK) {
        float4 e = *(const float4*)&ek[gk * DIM + d0 + db];
        float4 w = *(const float4*)&vv[gk * DIM + d0 + db];
        Bd[kb][db + 0] = e.x; Bd[kb][db + 1] = e.y; Bd[kb][db + 2] = e.z; Bd[kb][db + 3] = e.w;
        Bn[kb][db + 0] = e.x * w.x; Bn[kb][db + 1] = e.y * w.y;
        Bn[kb][db + 2] = e.z * w.z; Bn[kb][db + 3] = e.w * w.w;
      } else {
        Bd[kb][db + 0] = 0.f; Bd[kb][db + 1] = 0.f; Bd[kb][db + 2] = 0.f; Bd[kb][db + 3] = 0.f;
        Bn[kb][db + 0] = 0.f; Bn[kb][db + 1] = 0.f; Bn[kb][db + 2] = 0.f; Bn[kb][db + 3] = 0.f;
      }
    }
    __syncthreads();
#pragma unroll
    for (int kk = 0; kk < 32; ++kk) {
      float2 a2 = *(const float2*)&As[kk][ty * 2];
      float4 n4 = *(const float4*)&Bn[kk][tx * 4];
      float4 d4 = *(const float4*)&Bd[kk][tx * 4];
      float av[2] = {a2.x, a2.y};
      float nv[4] = {n4.x, n4.y, n4.z, n4.w};
      float dv[4] = {d4.x, d4.y, d4.z, d4.w};
#pragma unroll
      for (int i = 0; i < 2; ++i)
#pragma unroll
        for (int j = 0; j < 4; ++j) {
          an[i][j] = fmaf(av[i], nv[j], an[i][j]);
          ad[i][j] = fmaf(av[i], dv[j], ad[i][j]);
        }
    }
    __syncthreads();
  }
#pragma unroll
  for (int i = 0; i < 2; ++i) {
    int gr = m0 + ty * 2 + i;
    if (gr < NTOK) {
      float4 on = {an[i][0], an[i][1], an[i][2], an[i][3]};
      float4 od = {ad[i][0], ad[i][1], ad[i][2], ad[i][3]};
      *(float4*)&nump[(s * NTOK + gr) * DIM + d0 + tx * 4] = on;
      *(float4*)&denp[(s * NTOK + gr) * DIM + d0 + tx * 4] = od;
    }
  }
}

// attn = q * (sum nump)/(sum denp)   grid 392, 256 thr
__global__ void gate_kernel(const float* __restrict__ q, const float* __restrict__ nump,
                            const float* __restrict__ denp, float* __restrict__ attn) {
  int e = blockIdx.x * 256 + threadIdx.x;  // < 100352
  float num = 0.f, den = 0.f;
#pragma unroll
  for (int s = 0; s < 4; ++s) {
    num += nump[s * NTOK * DIM + e];
    den += denp[s * NTOK * DIM + e];
  }
  attn[e] = q[e] * (num / den);
}

// t2 = attn @ wo^T + bo + xt   grid (13, 2), 256 thr
__global__ __launch_bounds__(256) void proj_gemm(
    const float* __restrict__ attn, const float* __restrict__ wo,
    const float* __restrict__ bo, const float* __restrict__ xt, float* __restrict__ t2) {
  __shared__ float As[32][64];
  __shared__ float Bs[32][64];
  int tid = threadIdx.x;
  int m0 = blockIdx.x * 64, n0 = blockIdx.y * 64;
  int tx = tid & 15, ty = tid >> 4;
  int r = tid >> 2, kq = (tid & 3) * 8;
  int gm = m0 + r; if (gm > NTOK - 1) gm = NTOK - 1;
  float acc[4][4] = {};
  for (int kt = 0; kt < 4; ++kt) {
    int k0 = kt * 32;
#pragma unroll
    for (int j = 0; j < 8; ++j) As[kq + j][r] = attn[gm * DIM + k0 + kq + j];
#pragma unroll
    for (int j = 0; j < 8; ++j) Bs[kq + j][r] = wo[(n0 + r) * DIM + k0 + kq + j];
    __syncthreads();
#pragma unroll
    for (int kk = 0; kk < 32; ++kk) {
      float4 a4 = *(const float4*)&As[kk][ty * 4];
      float4 b4 = *(const float4*)&Bs[kk][tx * 4];
      float av[4] = {a4.x, a4.y, a4.z, a4.w};
      float bv[4] = {b4.x, b4.y, b4.z, b4.w};
#pragma unroll
      for (int i = 0; i < 4; ++i)
#pragma unroll
        for (int j = 0; j < 4; ++j) acc[i][j] = fmaf(av[i], bv[j], acc[i][j]);
    }
    __syncthreads();
  }
  int c0 = n0 + tx * 4;
  float4 bias = *(const float4*)&bo[c0];
#pragma unroll
  for (int i = 0; i < 4; ++i) {
    int gr = m0 + ty * 4 + i;
    if (gr < NTOK) {
      float4 t = *(const float4*)&xt[gr * DIM + c0];
      float4 o = {acc[i][0] + bias.x + t.x, acc[i][1] + bias.y + t.y,
                  acc[i][2] + bias.z + t.z, acc[i][3] + bias.w + t.w};
      *(float4*)&t2[gr * DIM + c0] = o;
    }
  }
}

// ff1 = gelu(fn @ w1^T + b1)   grid (13, 8), 256 thr
__global__ __launch_bounds__(256) void ff1_gemm(
    const float* __restrict__ fn, const float* __restrict__ w1,
    const float* __restrict__ b1, float* __restrict__ ff1) {
  __shared__ float As[32][64];
  __shared__ float Bs[32][64];
  int tid = threadIdx.x;
  int m0 = blockIdx.x * 64, n0 = blockIdx.y * 64;
  int tx = tid & 15, ty = tid >> 4;
  int r = tid >> 2, kq = (tid & 3) * 8;
  int gm = m0 + r; if (gm > NTOK - 1) gm = NTOK - 1;
  float acc[4][4] = {};
  for (int kt = 0; kt < 4; ++kt) {
    int k0 = kt * 32;
#pragma unroll
    for (int j = 0; j < 8; ++j) As[kq + j][r] = fn[gm * DIM + k0 + kq + j];
#pragma unroll
    for (int j = 0; j < 8; ++j) Bs[kq + j][r] = w1[(n0 + r) * DIM + k0 + kq + j];
    __syncthreads();
#pragma unroll
    for (int kk = 0; kk < 32; ++kk) {
      float4 a4 = *(const float4*)&As[kk][ty * 4];
      float4 b4 = *(const float4*)&Bs[kk][tx * 4];
      float av[4] = {a4.x, a4.y, a4.z, a4.w};
      float bv[4] = {b4.x, b4.y, b4.z, b4.w};
#pragma unroll
      for (int i = 0; i < 4; ++i)
#pragma unroll
        for (int j = 0; j < 4; ++j) acc[i][j] = fmaf(av[i], bv[j], acc[i][j]);
    }
    __syncthreads();
  }
  int c0 = n0 + tx * 4;
  float4 bias = *(const float4*)&b1[c0];
  float bb[4] = {bias.x, bias.y, bias.z, bias.w};
#pragma unroll
  for (int i = 0; i < 4; ++i) {
    int gr = m0 + ty * 4 + i;
    if (gr < NTOK) {
      float4 o;
      float* op = &o.x;
#pragma unroll
      for (int j = 0; j < 4; ++j) {
        float xv = acc[i][j] + bb[j];
        op[j] = 0.5f * xv * (1.0f + erff(xv * 0.70710678118654752f));
      }
      *(float4*)&ff1[gr * FFD + c0] = o;
    }
  }
}

// out[c][n] = ff1 @ w2^T + b2 + t2 (transposed write)  grid (13, 2), 512 thr
__global__ __launch_bounds__(512) void ff2_gemm(
    const float* __restrict__ ff1, const float* __restrict__ w2,
    const float* __restrict__ b2, const float* __restrict__ t2, float* __restrict__ out) {
  __shared__ float As[32][64];
  __shared__ float Bs[32][64];
  int tid = threadIdx.x;
  int m0 = blockIdx.x * 64, n0 = blockIdx.y * 64;
  int tx = tid & 15, ty = tid >> 4;        // 2 rows x 4 cols per thread
  int ra = tid >> 3, ka = (tid & 7) * 4;
  int gm = m0 + ra; if (gm > NTOK - 1) gm = NTOK - 1;
  float acc[2][4] = {};
  for (int kt = 0; kt < 16; ++kt) {
    int k0 = kt * 32;
    {
      float4 a = *(const float4*)&ff1[gm * FFD + k0 + ka];
      As[ka + 0][ra] = a.x; As[ka + 1][ra] = a.y;
      As[ka + 2][ra] = a.z; As[ka + 3][ra] = a.w;
      float4 bb = *(const float4*)&w2[(n0 + ra) * FFD + k0 + ka];
      Bs[ka + 0][ra] = bb.x; Bs[ka + 1][ra] = bb.y;
      Bs[ka + 2][ra] = bb.z; Bs[ka + 3][ra] = bb.w;
    }
    __syncthreads();
#pragma unroll
    for (int kk = 0; kk < 32; ++kk) {
      float2 a2 = *(const float2*)&As[kk][ty * 2];
      float4 b4 = *(const float4*)&Bs[kk][tx * 4];
      float av[2] = {a2.x, a2.y};
      float bv[4] = {b4.x, b4.y, b4.z, b4.w};
#pragma unroll
      for (int i = 0; i < 2; ++i)
#pragma unroll
        for (int j = 0; j < 4; ++j) acc[i][j] = fmaf(av[i], bv[j], acc[i][j]);
    }
    __syncthreads();
  }
  int c = n0 + tx * 4;
  float4 bias = *(const float4*)&b2[c];
#pragma unroll
  for (int i = 0; i < 2; ++i) {
    int gr = m0 + ty * 2 + i;
    if (gr < NTOK) {
      float4 t = *(const float4*)&t2[gr * DIM + c];
      out[(c + 0) * NTOK + gr] = acc[i][0] + bias.x + t.x;
      out[(c + 1) * NTOK + gr] = acc[i][1] + bias.y + t.y;
      out[(c + 2) * NTOK + gr] = acc[i][2] + bias.z + t.z;
      out[(c + 3) * NTOK + gr] = acc[i][3] + bias.w + t.w;
    }
  }
}

extern "C" void kernel_launch(void* const* d_in, const int* in_sizes, int n_in,
                              void* d_out, int out_size, void* d_ws, size_t ws_size,
                              hipStream_t stream) {
  const float* x   = (const float*)d_in[0];
  const float* wq  = (const float*)d_in[1];
  const float* wk  = (const float*)d_in[2];
  const float* wv  = (const float*)d_in[3];
  const float* wo  = (const float*)d_in[4];
  const float* bo  = (const float*)d_in[5];
  const float* pu  = (const float*)d_in[6];
  const float* pv  = (const float*)d_in[7];
  const float* g1  = (const float*)d_in[8];
  const float* b1n = (const float*)d_in[9];
  const float* g2  = (const float*)d_in[10];
  const float* b2n = (const float*)d_in[11];
  const float* w1  = (const float*)d_in[12];
  const float* b1f = (const float*)d_in[13];
  const float* w2  = (const float*)d_in[14];
  const float* b2f = (const float*)d_in[15];
  float* out = (float*)d_out;

  float* ws = (float*)d_ws;
  float* xt   = ws;                 // [784,128] raw t
  float* xn   = ws + 100352;        // [784,128] LN1 out; reused as attn
  float* q    = ws + 200704;        // [784,128]
  float* ek   = ws + 301056;        // [784,128]
  float* vv   = ws + 401408;        // [784,128]
  float* t2   = ws + 501760;        // [784,128]
  float* fn   = ws + 602112;        // [784,128]
  float* W    = ws + 702464;        // [784,784]; reused as ff1 [784,512]
  float* nump = ws + 1317120;       // [4,784,128]
  float* denp = ws + 1718528;       // [4,784,128]

  ln_from_chw<<<NTOK, DIM, 0, stream>>>(x, g1, b1n, xn, xt);
  qkv_gemm<<<dim3(13, 6), 256, 0, stream>>>(xn, wq, wk, wv, q, ek, vv);
  posw_gemm<<<dim3(13, 13), 256, 0, stream>>>(pu, pv, W);
  agg_gemm<<<dim3(13, 2, 4), 512, 0, stream>>>(W, ek, vv, nump, denp);
  gate_kernel<<<392, 256, 0, stream>>>(q, nump, denp, xn);   // xn := attn
  proj_gemm<<<dim3(13, 2), 256, 0, stream>>>(xn, wo, bo, xt, t2);
  ln_rows<<<NTOK, DIM, 0, stream>>>(t2, g2, b2n, fn);
  ff1_gemm<<<dim3(13, 8), 256, 0, stream>>>(fn, w1, b1f, W); // W := ff1
  ff2_gemm<<<dim3(13, 2), 512, 0, stream>>>(W, w2, b2f, t2, out);
}

// Round 3
// 94.339 us; speedup vs baseline: 2.0161x; 1.0912x over previous
//
#include <hip/hip_runtime.h>
#include <math.h>

#define NTOK 784
#define DIM 128
#define FFD 512

// ---------- posw: W = exp(u @ v^T), grid (13,13), 256 thr ----------
__global__ __launch_bounds__(256) void posw_gemm(
    const float* __restrict__ pu, const float* __restrict__ pv, float* __restrict__ W) {
  __shared__ float As[32][64];
  __shared__ float Bs[32][64];
  int tid = threadIdx.x;
  int m0 = blockIdx.x * 64, n0 = blockIdx.y * 64;
  int tx = tid & 15, ty = tid >> 4;
  int r = tid >> 2, kq = (tid & 3) * 8;
  int gm = m0 + r; if (gm > NTOK - 1) gm = NTOK - 1;
  int gn = n0 + r; if (gn > NTOK - 1) gn = NTOK - 1;
  float acc[4][4] = {};
  for (int kt = 0; kt < 4; ++kt) {
    int k0 = kt * 32;
#pragma unroll
    for (int j = 0; j < 8; ++j) As[kq + j][r] = pu[gm * DIM + k0 + kq + j];
#pragma unroll
    for (int j = 0; j < 8; ++j) Bs[kq + j][r] = pv[gn * DIM + k0 + kq + j];
    __syncthreads();
#pragma unroll
    for (int kk = 0; kk < 32; ++kk) {
      float4 a4 = *(const float4*)&As[kk][ty * 4];
      float4 b4 = *(const float4*)&Bs[kk][tx * 4];
      float av[4] = {a4.x, a4.y, a4.z, a4.w};
      float bv[4] = {b4.x, b4.y, b4.z, b4.w};
#pragma unroll
      for (int i = 0; i < 4; ++i)
#pragma unroll
        for (int j = 0; j < 4; ++j) acc[i][j] = fmaf(av[i], bv[j], acc[i][j]);
    }
    __syncthreads();
  }
  int c0 = n0 + tx * 4;
  if (c0 + 3 < NTOK) {
#pragma unroll
    for (int i = 0; i < 4; ++i) {
      int gr = m0 + ty * 4 + i;
      if (gr < NTOK) {
        float4 o = {expf(acc[i][0]), expf(acc[i][1]), expf(acc[i][2]), expf(acc[i][3])};
        *(float4*)&W[gr * NTOK + c0] = o;
      }
    }
  }
}

// ---------- fused LN1 + qkv, grid (13,6), 256 thr ----------
__global__ __launch_bounds__(256) void qkv_ln_gemm(
    const float* __restrict__ x, const float* __restrict__ g, const float* __restrict__ b,
    const float* __restrict__ wq, const float* __restrict__ wk, const float* __restrict__ wv,
    float* __restrict__ q, float* __restrict__ ek, float* __restrict__ vv) {
  __shared__ float Xs[DIM][64];   // k-major [c][n]
  __shared__ float Bs[DIM][64];   // [k][r]
  __shared__ float redS[4][64], redQ[4][64];
  int tid = threadIdx.x;
  int m0 = blockIdx.x * 64;
  int ct = blockIdx.y;
  int wsel = ct >> 1;
  int n0 = (ct & 1) * 64;
  const float* B = (wsel == 0) ? wq : (wsel == 1) ? wk : wv;

  // stage x tile (transpose from [C,N])
  if (m0 + 64 <= NTOK) {
#pragma unroll
    for (int it = 0; it < 8; ++it) {
      int idx = it * 256 + tid;
      int c = idx >> 4, j4 = (idx & 15) * 4;
      float4 v = *(const float4*)&x[c * NTOK + m0 + j4];
      Xs[c][j4 + 0] = v.x; Xs[c][j4 + 1] = v.y; Xs[c][j4 + 2] = v.z; Xs[c][j4 + 3] = v.w;
    }
  } else {
#pragma unroll
    for (int it = 0; it < 8; ++it) {
      int idx = it * 256 + tid;
      int c = idx >> 4, j4 = (idx & 15) * 4;
#pragma unroll
      for (int u = 0; u < 4; ++u) {
        int n = m0 + j4 + u; if (n > NTOK - 1) n = NTOK - 1;
        Xs[c][j4 + u] = x[c * NTOK + n];
      }
    }
  }
  __syncthreads();

  // LN over c per column n
  int n = tid & 63, grp = tid >> 6;
  float s = 0.f, ss = 0.f;
  for (int c = grp * 32; c < grp * 32 + 32; ++c) { float v = Xs[c][n]; s += v; ss += v * v; }
  redS[grp][n] = s; redQ[grp][n] = ss;
  __syncthreads();
  float sum = redS[0][n] + redS[1][n] + redS[2][n] + redS[3][n];
  float sq  = redQ[0][n] + redQ[1][n] + redQ[2][n] + redQ[3][n];
  float mu = sum * (1.0f / DIM);
  float var = sq * (1.0f / DIM) - mu * mu;
  float rs = rsqrtf(var + 1e-5f);
  for (int c = grp * 32; c < grp * 32 + 32; ++c)
    Xs[c][n] = (Xs[c][n] - mu) * rs * g[c] + b[c];

  // stage weight block
  int r = tid >> 2, kc = tid & 3;
#pragma unroll
  for (int j = 0; j < 8; ++j) {
    int k = kc * 32 + j * 4;
    float4 v = *(const float4*)&B[(n0 + r) * DIM + k];
    Bs[k + 0][r] = v.x; Bs[k + 1][r] = v.y; Bs[k + 2][r] = v.z; Bs[k + 3][r] = v.w;
  }
  __syncthreads();

  int tx = tid & 15, ty = tid >> 4;
  float acc[4][4] = {};
#pragma unroll 4
  for (int kk = 0; kk < DIM; ++kk) {
    float4 a4 = *(const float4*)&Xs[kk][ty * 4];
    float4 b4 = *(const float4*)&Bs[kk][tx * 4];
    float av[4] = {a4.x, a4.y, a4.z, a4.w};
    float bv[4] = {b4.x, b4.y, b4.z, b4.w};
#pragma unroll
    for (int i = 0; i < 4; ++i)
#pragma unroll
      for (int j = 0; j < 4; ++j) acc[i][j] = fmaf(av[i], bv[j], acc[i][j]);
  }
  int c0 = n0 + tx * 4;
  float* dst = (wsel == 0) ? q : (wsel == 1) ? ek : vv;
#pragma unroll
  for (int i = 0; i < 4; ++i) {
    int gr = m0 + ty * 4 + i;
    if (gr < NTOK) {
      float4 o;
      if (wsel == 0) {
        o.x = 1.0f / (1.0f + expf(-acc[i][0]));
        o.y = 1.0f / (1.0f + expf(-acc[i][1]));
        o.z = 1.0f / (1.0f + expf(-acc[i][2]));
        o.w = 1.0f / (1.0f + expf(-acc[i][3]));
      } else if (wsel == 1) {
        o.x = expf(acc[i][0]); o.y = expf(acc[i][1]);
        o.z = expf(acc[i][2]); o.w = expf(acc[i][3]);
      } else {
        o.x = acc[i][0]; o.y = acc[i][1]; o.z = acc[i][2]; o.w = acc[i][3];
      }
      *(float4*)&dst[gr * DIM + c0] = o;
    }
  }
}

// ---------- agg: K-split partials of W @ [ek*vv | ek], grid (13,2,4), 512 thr ----------
__global__ __launch_bounds__(512) void agg_gemm(
    const float* __restrict__ W, const float* __restrict__ ek,
    const float* __restrict__ vv, float* __restrict__ nump, float* __restrict__ denp) {
  __shared__ float As[32][64];
  __shared__ float Bn[32][64];
  __shared__ float Bd[32][64];
  int tid = threadIdx.x;
  int m0 = blockIdx.x * 64, d0 = blockIdx.y * 64, s = blockIdx.z;
  int tx = tid & 15, ty = tid >> 4;
  int ra = tid >> 3, ka = (tid & 7) * 4;
  int kb = tid >> 4, db = (tid & 15) * 4;
  int gm = m0 + ra; if (gm > NTOK - 1) gm = NTOK - 1;
  float an[2][4] = {}, ad[2][4] = {};
  int ktlo = (s * 25) / 4, kthi = ((s + 1) * 25) / 4;
  for (int kt = ktlo; kt < kthi; ++kt) {
    int k0 = kt * 32;
    if (k0 + 32 <= NTOK) {
      float4 a = *(const float4*)&W[gm * NTOK + k0 + ka];
      As[ka + 0][ra] = a.x; As[ka + 1][ra] = a.y;
      As[ka + 2][ra] = a.z; As[ka + 3][ra] = a.w;
      int gk = k0 + kb;
      float4 e = *(const float4*)&ek[gk * DIM + d0 + db];
      float4 w = *(const float4*)&vv[gk * DIM + d0 + db];
      Bd[kb][db + 0] = e.x; Bd[kb][db + 1] = e.y; Bd[kb][db + 2] = e.z; Bd[kb][db + 3] = e.w;
      Bn[kb][db + 0] = e.x * w.x; Bn[kb][db + 1] = e.y * w.y;
      Bn[kb][db + 2] = e.z * w.z; Bn[kb][db + 3] = e.w * w.w;
    } else {
#pragma unroll
      for (int j = 0; j < 4; ++j) {
        int gk = k0 + ka + j;
        As[ka + j][ra] = (gk < NTOK) ? W[gm * NTOK + gk] : 0.f;
      }
      int gk = k0 + kb;
      if (gk < NTOK) {
        float4 e = *(const float4*)&ek[gk * DIM + d0 + db];
        float4 w = *(const float4*)&vv[gk * DIM + d0 + db];
        Bd[kb][db + 0] = e.x; Bd[kb][db + 1] = e.y; Bd[kb][db + 2] = e.z; Bd[kb][db + 3] = e.w;
        Bn[kb][db + 0] = e.x * w.x; Bn[kb][db + 1] = e.y * w.y;
        Bn[kb][db + 2] = e.z * w.z; Bn[kb][db + 3] = e.w * w.w;
      } else {
        Bd[kb][db + 0] = 0.f; Bd[kb][db + 1] = 0.f; Bd[kb][db + 2] = 0.f; Bd[kb][db + 3] = 0.f;
        Bn[kb][db + 0] = 0.f; Bn[kb][db + 1] = 0.f; Bn[kb][db + 2] = 0.f; Bn[kb][db + 3] = 0.f;
      }
    }
    __syncthreads();
#pragma unroll
    for (int kk = 0; kk < 32; ++kk) {
      float2 a2 = *(const float2*)&As[kk][ty * 2];
      float4 n4 = *(const float4*)&Bn[kk][tx * 4];
      float4 d4 = *(const float4*)&Bd[kk][tx * 4];
      float av[2] = {a2.x, a2.y};
      float nv[4] = {n4.x, n4.y, n4.z, n4.w};
      float dv[4] = {d4.x, d4.y, d4.z, d4.w};
#pragma unroll
      for (int i = 0; i < 2; ++i)
#pragma unroll
        for (int j = 0; j < 4; ++j) {
          an[i][j] = fmaf(av[i], nv[j], an[i][j]);
          ad[i][j] = fmaf(av[i], dv[j], ad[i][j]);
        }
    }
    __syncthreads();
  }
#pragma unroll
  for (int i = 0; i < 2; ++i) {
    int gr = m0 + ty * 2 + i;
    if (gr < NTOK) {
      float4 on = {an[i][0], an[i][1], an[i][2], an[i][3]};
      float4 od = {ad[i][0], ad[i][1], ad[i][2], ad[i][3]};
      *(float4*)&nump[(s * NTOK + gr) * DIM + d0 + tx * 4] = on;
      *(float4*)&denp[(s * NTOK + gr) * DIM + d0 + tx * 4] = od;
    }
  }
}

// ---------- fused gate + O-proj + residual + LN2, grid 49, 512 thr ----------
__global__ __launch_bounds__(512) void proj_gate_ln(
    const float* __restrict__ q, const float* __restrict__ nump,
    const float* __restrict__ denp, const float* __restrict__ wo,
    const float* __restrict__ bo, const float* __restrict__ x,
    const float* __restrict__ g2, const float* __restrict__ b2n,
    float* __restrict__ t2, float* __restrict__ fn) {
  __shared__ float At[DIM][17];    // attn tile, k-major [c][n], padded
  __shared__ float Bs[DIM][DIM];   // wo, k-major [k][c]
  int tid = threadIdx.x;
  int m0 = blockIdx.x * 16;        // 49*16 = 784 exact

  // stage attn tile: attn[n][c] = q * sum(num)/sum(den)
  {
    int nn = tid >> 5, c4 = (tid & 31) * 4;
    int base = (m0 + nn) * DIM + c4;
    float4 qv = *(const float4*)&q[base];
    float4 nv = {0.f, 0.f, 0.f, 0.f}, dv = {0.f, 0.f, 0.f, 0.f};
#pragma unroll
    for (int s = 0; s < 4; ++s) {
      float4 a = *(const float4*)&nump[s * NTOK * DIM + base];
      float4 d = *(const float4*)&denp[s * NTOK * DIM + base];
      nv.x += a.x; nv.y += a.y; nv.z += a.z; nv.w += a.w;
      dv.x += d.x; dv.y += d.y; dv.z += d.z; dv.w += d.w;
    }
    At[c4 + 0][nn] = qv.x * (nv.x / dv.x);
    At[c4 + 1][nn] = qv.y * (nv.y / dv.y);
    At[c4 + 2][nn] = qv.z * (nv.z / dv.z);
    At[c4 + 3][nn] = qv.w * (nv.w / dv.w);
  }
  // stage full wo (k-major)
  {
    int r = tid >> 2, kc = tid & 3;
#pragma unroll
    for (int j = 0; j < 8; ++j) {
      int k = kc * 32 + j * 4;
      float4 v = *(const float4*)&wo[r * DIM + k];
      Bs[k + 0][r] = v.x; Bs[k + 1][r] = v.y; Bs[k + 2][r] = v.z; Bs[k + 3][r] = v.w;
    }
  }
  __syncthreads();

  int ty = tid >> 5, tx = tid & 31;   // 1 row x 4 cols per thread
  float acc[4] = {0.f, 0.f, 0.f, 0.f};
#pragma unroll 4
  for (int kk = 0; kk < DIM; ++kk) {
    float a = At[kk][ty];
    float4 b4 = *(const float4*)&Bs[kk][tx * 4];
    acc[0] = fmaf(a, b4.x, acc[0]);
    acc[1] = fmaf(a, b4.y, acc[1]);
    acc[2] = fmaf(a, b4.z, acc[2]);
    acc[3] = fmaf(a, b4.w, acc[3]);
  }
  int gn = m0 + ty;
  int c0 = tx * 4;
  float4 bias = *(const float4*)&bo[c0];
  float4 o;
  o.x = acc[0] + bias.x + x[(c0 + 0) * NTOK + gn];
  o.y = acc[1] + bias.y + x[(c0 + 1) * NTOK + gn];
  o.z = acc[2] + bias.z + x[(c0 + 2) * NTOK + gn];
  o.w = acc[3] + bias.w + x[(c0 + 3) * NTOK + gn];
  *(float4*)&t2[gn * DIM + c0] = o;

  // LN2 in registers: 32 lanes per row, xor masks stay within the row group
  float s = o.x + o.y + o.z + o.w;
  float ss = o.x * o.x + o.y * o.y + o.z * o.z + o.w * o.w;
#pragma unroll
  for (int off = 1; off < 32; off <<= 1) {
    s += __shfl_xor(s, off);
    ss += __shfl_xor(ss, off);
  }
  float mu = s * (1.0f / DIM);
  float var = ss * (1.0f / DIM) - mu * mu;
  float rs = rsqrtf(var + 1e-5f);
  float4 gg = *(const float4*)&g2[c0];
  float4 bb = *(const float4*)&b2n[c0];
  float4 f;
  f.x = (o.x - mu) * rs * gg.x + bb.x;
  f.y = (o.y - mu) * rs * gg.y + bb.y;
  f.z = (o.z - mu) * rs * gg.z + bb.z;
  f.w = (o.w - mu) * rs * gg.w + bb.w;
  *(float4*)&fn[gn * DIM + c0] = f;
}

// ---------- ff1 = gelu(fn @ w1^T + b1), grid (13,8), 256 thr ----------
__global__ __launch_bounds__(256) void ff1_gemm(
    const float* __restrict__ fn, const float* __restrict__ w1,
    const float* __restrict__ b1, float* __restrict__ ff1) {
  __shared__ float As[32][64];
  __shared__ float Bs[32][64];
  int tid = threadIdx.x;
  int m0 = blockIdx.x * 64, n0 = blockIdx.y * 64;
  int tx = tid & 15, ty = tid >> 4;
  int r = tid >> 2, kq = (tid & 3) * 8;
  int gm = m0 + r; if (gm > NTOK - 1) gm = NTOK - 1;
  float acc[4][4] = {};
  for (int kt = 0; kt < 4; ++kt) {
    int k0 = kt * 32;
#pragma unroll
    for (int j = 0; j < 8; ++j) As[kq + j][r] = fn[gm * DIM + k0 + kq + j];
#pragma unroll
    for (int j = 0; j < 8; ++j) Bs[kq + j][r] = w1[(n0 + r) * DIM + k0 + kq + j];
    __syncthreads();
#pragma unroll
    for (int kk = 0; kk < 32; ++kk) {
      float4 a4 = *(const float4*)&As[kk][ty * 4];
      float4 b4 = *(const float4*)&Bs[kk][tx * 4];
      float av[4] = {a4.x, a4.y, a4.z, a4.w};
      float bv[4] = {b4.x, b4.y, b4.z, b4.w};
#pragma unroll
      for (int i = 0; i < 4; ++i)
#pragma unroll
        for (int j = 0; j < 4; ++j) acc[i][j] = fmaf(av[i], bv[j], acc[i][j]);
    }
    __syncthreads();
  }
  int c0 = n0 + tx * 4;
  float4 bias = *(const float4*)&b1[c0];
  float bb[4] = {bias.x, bias.y, bias.z, bias.w};
#pragma unroll
  for (int i = 0; i < 4; ++i) {
    int gr = m0 + ty * 4 + i;
    if (gr < NTOK) {
      float4 o;
      float* op = &o.x;
#pragma unroll
      for (int j = 0; j < 4; ++j) {
        float xv = acc[i][j] + bb[j];
        op[j] = 0.5f * xv * (1.0f + erff(xv * 0.70710678118654752f));
      }
      *(float4*)&ff1[gr * FFD + c0] = o;
    }
  }
}

// ---------- ff2 + residual, transposed write, grid (13,2), 512 thr ----------
__global__ __launch_bounds__(512) void ff2_gemm(
    const float* __restrict__ ff1, const float* __restrict__ w2,
    const float* __restrict__ b2, const float* __restrict__ t2, float* __restrict__ out) {
  __shared__ float As[32][64];
  __shared__ float Bs[32][64];
  int tid = threadIdx.x;
  int m0 = blockIdx.x * 64, n0 = blockIdx.y * 64;
  int tx = tid & 15, ty = tid >> 4;
  int ra = tid >> 3, ka = (tid & 7) * 4;
  int gm = m0 + ra; if (gm > NTOK - 1) gm = NTOK - 1;
  float acc[2][4] = {};
  for (int kt = 0; kt < 16; ++kt) {
    int k0 = kt * 32;
    {
      float4 a = *(const float4*)&ff1[gm * FFD + k0 + ka];
      As[ka + 0][ra] = a.x; As[ka + 1][ra] = a.y;
      As[ka + 2][ra] = a.z; As[ka + 3][ra] = a.w;
      float4 bb = *(const float4*)&w2[(n0 + ra) * FFD + k0 + ka];
      Bs[ka + 0][ra] = bb.x; Bs[ka + 1][ra] = bb.y;
      Bs[ka + 2][ra] = bb.z; Bs[ka + 3][ra] = bb.w;
    }
    __syncthreads();
#pragma unroll
    for (int kk = 0; kk < 32; ++kk) {
      float2 a2 = *(const float2*)&As[kk][ty * 2];
      float4 b4 = *(const float4*)&Bs[kk][tx * 4];
      float av[2] = {a2.x, a2.y};
      float bv[4] = {b4.x, b4.y, b4.z, b4.w};
#pragma unroll
      for (int i = 0; i < 2; ++i)
#pragma unroll
        for (int j = 0; j < 4; ++j) acc[i][j] = fmaf(av[i], bv[j], acc[i][j]);
    }
    __syncthreads();
  }
  int c = n0 + tx * 4;
  float4 bias = *(const float4*)&b2[c];
#pragma unroll
  for (int i = 0; i < 2; ++i) {
    int gr = m0 + ty * 2 + i;
    if (gr < NTOK) {
      float4 t = *(const float4*)&t2[gr * DIM + c];
      out[(c + 0) * NTOK + gr] = acc[i][0] + bias.x + t.x;
      out[(c + 1) * NTOK + gr] = acc[i][1] + bias.y + t.y;
      out[(c + 2) * NTOK + gr] = acc[i][2] + bias.z + t.z;
      out[(c + 3) * NTOK + gr] = acc[i][3] + bias.w + t.w;
    }
  }
}

extern "C" void kernel_launch(void* const* d_in, const int* in_sizes, int n_in,
                              void* d_out, int out_size, void* d_ws, size_t ws_size,
                              hipStream_t stream) {
  const float* x   = (const float*)d_in[0];
  const float* wq  = (const float*)d_in[1];
  const float* wk  = (const float*)d_in[2];
  const float* wv  = (const float*)d_in[3];
  const float* wo  = (const float*)d_in[4];
  const float* bo  = (const float*)d_in[5];
  const float* pu  = (const float*)d_in[6];
  const float* pv  = (const float*)d_in[7];
  const float* g1  = (const float*)d_in[8];
  const float* b1n = (const float*)d_in[9];
  const float* g2  = (const float*)d_in[10];
  const float* b2n = (const float*)d_in[11];
  const float* w1  = (const float*)d_in[12];
  const float* b1f = (const float*)d_in[13];
  const float* w2  = (const float*)d_in[14];
  const float* b2f = (const float*)d_in[15];
  float* out = (float*)d_out;

  float* ws = (float*)d_ws;
  float* q    = ws;                 // [784,128]
  float* ek   = ws + 100352;        // [784,128]
  float* vv   = ws + 200704;        // [784,128]
  float* t2   = ws + 301056;        // [784,128]
  float* fn   = ws + 401408;        // [784,128]
  float* W    = ws + 501760;        // [784,784]; reused as ff1 [784,512]
  float* nump = ws + 1116416;       // [4,784,128]
  float* denp = ws + 1517824;       // [4,784,128]

  posw_gemm<<<dim3(13, 13), 256, 0, stream>>>(pu, pv, W);
  qkv_ln_gemm<<<dim3(13, 6), 256, 0, stream>>>(x, g1, b1n, wq, wk, wv, q, ek, vv);
  agg_gemm<<<dim3(13, 2, 4), 512, 0, stream>>>(W, ek, vv, nump, denp);
  proj_gate_ln<<<49, 512, 0, stream>>>(q, nump, denp, wo, bo, x, g2, b2n, t2, fn);
  ff1_gemm<<<dim3(13, 8), 256, 0, stream>>>(fn, w1, b1f, W);   // W := ff1
  ff2_gemm<<<dim3(13, 2), 512, 0, stream>>>(W, w2, b2f, t2, out);
}

// Round 4
// 79.344 us; speedup vs baseline: 2.3972x; 1.1890x over previous
//
#include <hip/hip_runtime.h>
#include <math.h>

#define NTOK 784
#define DIM 128
#define FFD 512

// ================= K1: posw (169 blocks) || LN1+qkv (78 blocks) =================
__global__ __launch_bounds__(256) void posw_qkv(
    const float* __restrict__ pu, const float* __restrict__ pv, float* __restrict__ W,
    const float* __restrict__ x, const float* __restrict__ g, const float* __restrict__ b,
    const float* __restrict__ wq, const float* __restrict__ wk, const float* __restrict__ wv,
    float* __restrict__ q, float* __restrict__ ek, float* __restrict__ vv) {
  __shared__ float smem[16896];  // 66 KB, role-dependent layout
  int tid = threadIdx.x;

  if (blockIdx.x < 169) {
    // ---------- posw role: W = exp(u @ v^T), 64x64 tile ----------
    float (*As)[64] = (float(*)[64])smem;          // [32][64]
    float (*Bs)[64] = (float(*)[64])(smem + 2048); // [32][64]
    int pb = blockIdx.x;
    int m0 = (pb % 13) * 64, n0 = (pb / 13) * 64;
    int tx = tid & 15, ty = tid >> 4;
    int r = tid >> 2, kq = (tid & 3) * 8;
    int gm = m0 + r; if (gm > NTOK - 1) gm = NTOK - 1;
    int gn = n0 + r; if (gn > NTOK - 1) gn = NTOK - 1;
    float acc[4][4] = {};
    for (int kt = 0; kt < 4; ++kt) {
      int k0 = kt * 32;
#pragma unroll
      for (int j = 0; j < 8; ++j) As[kq + j][r] = pu[gm * DIM + k0 + kq + j];
#pragma unroll
      for (int j = 0; j < 8; ++j) Bs[kq + j][r] = pv[gn * DIM + k0 + kq + j];
      __syncthreads();
#pragma unroll
      for (int kk = 0; kk < 32; ++kk) {
        float4 a4 = *(const float4*)&As[kk][ty * 4];
        float4 b4 = *(const float4*)&Bs[kk][tx * 4];
        float av[4] = {a4.x, a4.y, a4.z, a4.w};
        float bv[4] = {b4.x, b4.y, b4.z, b4.w};
#pragma unroll
        for (int i = 0; i < 4; ++i)
#pragma unroll
          for (int j = 0; j < 4; ++j) acc[i][j] = fmaf(av[i], bv[j], acc[i][j]);
      }
      __syncthreads();
    }
    int c0 = n0 + tx * 4;
    if (c0 + 3 < NTOK) {
#pragma unroll
      for (int i = 0; i < 4; ++i) {
        int gr = m0 + ty * 4 + i;
        if (gr < NTOK) {
          float4 o = {expf(acc[i][0]), expf(acc[i][1]), expf(acc[i][2]), expf(acc[i][3])};
          *(float4*)&W[gr * NTOK + c0] = o;
        }
      }
    }
  } else {
    // ---------- qkv role: fused LN1 + one of {q,k,v} half ----------
    float (*Xs)[64] = (float(*)[64])smem;            // [128][64]
    float (*Bs)[64] = (float(*)[64])(smem + 8192);   // [128][64]
    float (*redS)[64] = (float(*)[64])(smem + 16384);
    float (*redQ)[64] = (float(*)[64])(smem + 16640);
    int bid = blockIdx.x - 169;
    int m0 = (bid % 13) * 64;
    int ct = bid / 13;
    int wsel = ct >> 1;
    int n0 = (ct & 1) * 64;
    const float* B = (wsel == 0) ? wq : (wsel == 1) ? wk : wv;

    if (m0 + 64 <= NTOK) {
#pragma unroll
      for (int it = 0; it < 8; ++it) {
        int idx = it * 256 + tid;
        int c = idx >> 4, j4 = (idx & 15) * 4;
        float4 v = *(const float4*)&x[c * NTOK + m0 + j4];
        Xs[c][j4 + 0] = v.x; Xs[c][j4 + 1] = v.y; Xs[c][j4 + 2] = v.z; Xs[c][j4 + 3] = v.w;
      }
    } else {
#pragma unroll
      for (int it = 0; it < 8; ++it) {
        int idx = it * 256 + tid;
        int c = idx >> 4, j4 = (idx & 15) * 4;
#pragma unroll
        for (int u = 0; u < 4; ++u) {
          int n = m0 + j4 + u; if (n > NTOK - 1) n = NTOK - 1;
          Xs[c][j4 + u] = x[c * NTOK + n];
        }
      }
    }
    __syncthreads();

    int n = tid & 63, grp = tid >> 6;
    float s = 0.f, ss = 0.f;
    for (int c = grp * 32; c < grp * 32 + 32; ++c) { float v = Xs[c][n]; s += v; ss += v * v; }
    redS[grp][n] = s; redQ[grp][n] = ss;
    __syncthreads();
    float sum = redS[0][n] + redS[1][n] + redS[2][n] + redS[3][n];
    float sq  = redQ[0][n] + redQ[1][n] + redQ[2][n] + redQ[3][n];
    float mu = sum * (1.0f / DIM);
    float var = sq * (1.0f / DIM) - mu * mu;
    float rs = rsqrtf(var + 1e-5f);
    for (int c = grp * 32; c < grp * 32 + 32; ++c)
      Xs[c][n] = (Xs[c][n] - mu) * rs * g[c] + b[c];

    int r = tid >> 2, kc = tid & 3;
#pragma unroll
    for (int j = 0; j < 8; ++j) {
      int k = kc * 32 + j * 4;
      float4 v = *(const float4*)&B[(n0 + r) * DIM + k];
      Bs[k + 0][r] = v.x; Bs[k + 1][r] = v.y; Bs[k + 2][r] = v.z; Bs[k + 3][r] = v.w;
    }
    __syncthreads();

    int tx = tid & 15, ty = tid >> 4;
    float acc[4][4] = {};
#pragma unroll 4
    for (int kk = 0; kk < DIM; ++kk) {
      float4 a4 = *(const float4*)&Xs[kk][ty * 4];
      float4 b4 = *(const float4*)&Bs[kk][tx * 4];
      float av[4] = {a4.x, a4.y, a4.z, a4.w};
      float bv[4] = {b4.x, b4.y, b4.z, b4.w};
#pragma unroll
      for (int i = 0; i < 4; ++i)
#pragma unroll
        for (int j = 0; j < 4; ++j) acc[i][j] = fmaf(av[i], bv[j], acc[i][j]);
    }
    int c0 = n0 + tx * 4;
    float* dst = (wsel == 0) ? q : (wsel == 1) ? ek : vv;
#pragma unroll
    for (int i = 0; i < 4; ++i) {
      int gr = m0 + ty * 4 + i;
      if (gr < NTOK) {
        float4 o;
        if (wsel == 0) {
          o.x = 1.0f / (1.0f + expf(-acc[i][0]));
          o.y = 1.0f / (1.0f + expf(-acc[i][1]));
          o.z = 1.0f / (1.0f + expf(-acc[i][2]));
          o.w = 1.0f / (1.0f + expf(-acc[i][3]));
        } else if (wsel == 1) {
          o.x = expf(acc[i][0]); o.y = expf(acc[i][1]);
          o.z = expf(acc[i][2]); o.w = expf(acc[i][3]);
        } else {
          o.x = acc[i][0]; o.y = acc[i][1]; o.z = acc[i][2]; o.w = acc[i][3];
        }
        *(float4*)&dst[gr * DIM + c0] = o;
      }
    }
  }
}

// ================= K2: agg, K-split 8, grid (13,2,8), 512 thr =================
__global__ __launch_bounds__(512) void agg_gemm(
    const float* __restrict__ W, const float* __restrict__ ek,
    const float* __restrict__ vv, float* __restrict__ nump, float* __restrict__ denp) {
  __shared__ float As[32][64];
  __shared__ float Bn[32][64];
  __shared__ float Bd[32][64];
  int tid = threadIdx.x;
  int m0 = blockIdx.x * 64, d0 = blockIdx.y * 64, s = blockIdx.z;
  int tx = tid & 15, ty = tid >> 4;
  int ra = tid >> 3, ka = (tid & 7) * 4;
  int kb = tid >> 4, db = (tid & 15) * 4;
  int gm = m0 + ra; if (gm > NTOK - 1) gm = NTOK - 1;
  float an[2][4] = {}, ad[2][4] = {};
  int ktlo = (s * 25) / 8, kthi = ((s + 1) * 25) / 8;
  for (int kt = ktlo; kt < kthi; ++kt) {
    int k0 = kt * 32;
    if (k0 + 32 <= NTOK) {
      float4 a = *(const float4*)&W[gm * NTOK + k0 + ka];
      As[ka + 0][ra] = a.x; As[ka + 1][ra] = a.y;
      As[ka + 2][ra] = a.z; As[ka + 3][ra] = a.w;
      int gk = k0 + kb;
      float4 e = *(const float4*)&ek[gk * DIM + d0 + db];
      float4 w = *(const float4*)&vv[gk * DIM + d0 + db];
      Bd[kb][db + 0] = e.x; Bd[kb][db + 1] = e.y; Bd[kb][db + 2] = e.z; Bd[kb][db + 3] = e.w;
      Bn[kb][db + 0] = e.x * w.x; Bn[kb][db + 1] = e.y * w.y;
      Bn[kb][db + 2] = e.z * w.z; Bn[kb][db + 3] = e.w * w.w;
    } else {
#pragma unroll
      for (int j = 0; j < 4; ++j) {
        int gk = k0 + ka + j;
        As[ka + j][ra] = (gk < NTOK) ? W[gm * NTOK + gk] : 0.f;
      }
      int gk = k0 + kb;
      if (gk < NTOK) {
        float4 e = *(const float4*)&ek[gk * DIM + d0 + db];
        float4 w = *(const float4*)&vv[gk * DIM + d0 + db];
        Bd[kb][db + 0] = e.x; Bd[kb][db + 1] = e.y; Bd[kb][db + 2] = e.z; Bd[kb][db + 3] = e.w;
        Bn[kb][db + 0] = e.x * w.x; Bn[kb][db + 1] = e.y * w.y;
        Bn[kb][db + 2] = e.z * w.z; Bn[kb][db + 3] = e.w * w.w;
      } else {
        Bd[kb][db + 0] = 0.f; Bd[kb][db + 1] = 0.f; Bd[kb][db + 2] = 0.f; Bd[kb][db + 3] = 0.f;
        Bn[kb][db + 0] = 0.f; Bn[kb][db + 1] = 0.f; Bn[kb][db + 2] = 0.f; Bn[kb][db + 3] = 0.f;
      }
    }
    __syncthreads();
#pragma unroll
    for (int kk = 0; kk < 32; ++kk) {
      float2 a2 = *(const float2*)&As[kk][ty * 2];
      float4 n4 = *(const float4*)&Bn[kk][tx * 4];
      float4 d4 = *(const float4*)&Bd[kk][tx * 4];
      float av[2] = {a2.x, a2.y};
      float nv[4] = {n4.x, n4.y, n4.z, n4.w};
      float dv[4] = {d4.x, d4.y, d4.z, d4.w};
#pragma unroll
      for (int i = 0; i < 2; ++i)
#pragma unroll
        for (int j = 0; j < 4; ++j) {
          an[i][j] = fmaf(av[i], nv[j], an[i][j]);
          ad[i][j] = fmaf(av[i], dv[j], ad[i][j]);
        }
    }
    __syncthreads();
  }
#pragma unroll
  for (int i = 0; i < 2; ++i) {
    int gr = m0 + ty * 2 + i;
    if (gr < NTOK) {
      float4 on = {an[i][0], an[i][1], an[i][2], an[i][3]};
      float4 od = {ad[i][0], ad[i][1], ad[i][2], ad[i][3]};
      *(float4*)&nump[(s * NTOK + gr) * DIM + d0 + tx * 4] = on;
      *(float4*)&denp[(s * NTOK + gr) * DIM + d0 + tx * 4] = od;
    }
  }
}

// ===== K3: gate + proj + residual + LN2 + ff1(gelu) + ff2 + residual + out^T =====
// 8 rows/block, 512 thr, grid 98. All intermediates in LDS (~48 KB).
#define NR 8
__global__ __launch_bounds__(512) void epilogue_fused(
    const float* __restrict__ q, const float* __restrict__ nump,
    const float* __restrict__ denp, const float* __restrict__ wo,
    const float* __restrict__ bo, const float* __restrict__ x,
    const float* __restrict__ g2, const float* __restrict__ b2n,
    const float* __restrict__ w1, const float* __restrict__ b1f,
    const float* __restrict__ w2, const float* __restrict__ b2f,
    float* __restrict__ out) {
  __shared__ float At[DIM][9];    // attn k-major (pad 9); reused for out^T
  __shared__ float T2[NR][DIM];   // residual accumulator
  __shared__ float Fn[DIM][9];    // LN2 output, k-major
  __shared__ float F1t[64][9];    // ff1 tile, k-major
  __shared__ float WtBuf[8320];   // [128][65] (wo/w1 tiles) or [64][130] (w2 tiles)
  int tid = threadIdx.x;
  int m0 = blockIdx.x * NR;       // 98*8 = 784 exact

  int n = tid >> 6, cl = tid & 63;  // wave <-> row mapping (64 lanes per row)

  // ---- Phase A: gate -> At, x residual preload -> T2
  {
    int c0 = cl * 2;
    int base = (m0 + n) * DIM + c0;
    float2 qv = *(const float2*)&q[base];
    float nx = 0.f, ny = 0.f, dx = 0.f, dy = 0.f;
#pragma unroll
    for (int s = 0; s < 8; ++s) {
      float2 a = *(const float2*)&nump[s * NTOK * DIM + base];
      float2 d = *(const float2*)&denp[s * NTOK * DIM + base];
      nx += a.x; ny += a.y; dx += d.x; dy += d.y;
    }
    At[c0][n] = qv.x * (nx / dx);
    At[c0 + 1][n] = qv.y * (ny / dy);
    int c = tid >> 2, nn = (tid & 3) * 2;
    float2 xv = *(const float2*)&x[c * NTOK + m0 + nn];
    T2[nn][c] = xv.x; T2[nn + 1][c] = xv.y;
  }
  __syncthreads();

  // ---- Phase B: O-proj (2 cout-tiles of 64), += into T2
  float (*Wt)[65] = (float(*)[65])WtBuf;
#pragma unroll
  for (int ct = 0; ct < 2; ++ct) {
#pragma unroll
    for (int it = 0; it < 4; ++it) {
      int idx = it * 512 + tid;
      int row = idx >> 5, kq = (idx & 31) * 4;
      float4 v = *(const float4*)&wo[(ct * 64 + row) * DIM + kq];
      Wt[kq + 0][row] = v.x; Wt[kq + 1][row] = v.y;
      Wt[kq + 2][row] = v.z; Wt[kq + 3][row] = v.w;
    }
    __syncthreads();
    float acc = 0.f;
#pragma unroll 8
    for (int k = 0; k < DIM; ++k) acc = fmaf(At[k][n], Wt[k][cl], acc);
    int c = ct * 64 + cl;
    T2[n][c] += acc + bo[c];
    __syncthreads();
  }

  // ---- Phase C: LN2 (one wave per row, 64-lane butterfly)
  {
    float v0 = T2[n][cl], v1 = T2[n][cl + 64];
    float s = v0 + v1, ss = v0 * v0 + v1 * v1;
#pragma unroll
    for (int off = 1; off < 64; off <<= 1) {
      s += __shfl_xor(s, off);
      ss += __shfl_xor(ss, off);
    }
    float mu = s * (1.0f / DIM);
    float var = ss * (1.0f / DIM) - mu * mu;
    float rs = rsqrtf(var + 1e-5f);
    Fn[cl][n] = (v0 - mu) * rs * g2[cl] + b2n[cl];
    Fn[cl + 64][n] = (v1 - mu) * rs * g2[cl + 64] + b2n[cl + 64];
  }
  __syncthreads();

  // ---- Phase D/E: ff1 + ff2 interleaved over 8 f-tiles of 64
  float acc2a = 0.f, acc2b = 0.f;
  int c0 = cl * 2;
  float (*Wt2)[130] = (float(*)[130])WtBuf;
  for (int ft = 0; ft < 8; ++ft) {
    int f0 = ft * 64;
    // stage w1 tile [f0..f0+64) -> Wt[cin][f_local]
#pragma unroll
    for (int it = 0; it < 4; ++it) {
      int idx = it * 512 + tid;
      int row = idx >> 5, kq = (idx & 31) * 4;
      float4 v = *(const float4*)&w1[(f0 + row) * DIM + kq];
      Wt[kq + 0][row] = v.x; Wt[kq + 1][row] = v.y;
      Wt[kq + 2][row] = v.z; Wt[kq + 3][row] = v.w;
    }
    __syncthreads();
    // ff1: one output per thread (n, f0+cl)
    float a1 = b1f[f0 + cl];
#pragma unroll 8
    for (int k = 0; k < DIM; ++k) a1 = fmaf(Fn[k][n], Wt[k][cl], a1);
    float ge = 0.5f * a1 * (1.0f + erff(a1 * 0.70710678118654752f));
    __syncthreads();               // everyone done reading Wt
    F1t[cl][n] = ge;
    // stage w2 tile -> Wt2[f_local][c] (transposed, padded stride 130)
#pragma unroll
    for (int it = 0; it < 4; ++it) {
      int idx = it * 512 + tid;
      int c = idx >> 4, fq = (idx & 15) * 4;
      float4 v = *(const float4*)&w2[c * FFD + f0 + fq];
      Wt2[fq + 0][c] = v.x; Wt2[fq + 1][c] = v.y;
      Wt2[fq + 2][c] = v.z; Wt2[fq + 3][c] = v.w;
    }
    __syncthreads();               // also covers F1t writes
    // ff2 partial: 2 outputs (n, c0), (n, c0+1)
#pragma unroll 8
    for (int f = 0; f < 64; ++f) {
      float p = F1t[f][n];
      float2 wv = *(const float2*)&Wt2[f][c0];
      acc2a = fmaf(p, wv.x, acc2a);
      acc2b = fmaf(p, wv.y, acc2b);
    }
    __syncthreads();
  }

  // ---- Epilogue: out = ff2 + b2 + t2, transposed write via LDS (reuse At)
  {
    float2 bb = *(const float2*)&b2f[c0];
    At[c0][n] = acc2a + bb.x + T2[n][c0];
    At[c0 + 1][n] = acc2b + bb.y + T2[n][c0 + 1];
  }
  __syncthreads();
  {
    int c = tid >> 2, nn = (tid & 3) * 2;
    float2 o = {At[c][nn], At[c][nn + 1]};
    *(float2*)&out[c * NTOK + m0 + nn] = o;
  }
}

extern "C" void kernel_launch(void* const* d_in, const int* in_sizes, int n_in,
                              void* d_out, int out_size, void* d_ws, size_t ws_size,
                              hipStream_t stream) {
  const float* x   = (const float*)d_in[0];
  const float* wq  = (const float*)d_in[1];
  const float* wk  = (const float*)d_in[2];
  const float* wv  = (const float*)d_in[3];
  const float* wo  = (const float*)d_in[4];
  const float* bo  = (const float*)d_in[5];
  const float* pu  = (const float*)d_in[6];
  const float* pv  = (const float*)d_in[7];
  const float* g1  = (const float*)d_in[8];
  const float* b1n = (const float*)d_in[9];
  const float* g2  = (const float*)d_in[10];
  const float* b2n = (const float*)d_in[11];
  const float* w1  = (const float*)d_in[12];
  const float* b1f = (const float*)d_in[13];
  const float* w2  = (const float*)d_in[14];
  const float* b2f = (const float*)d_in[15];
  float* out = (float*)d_out;

  float* ws = (float*)d_ws;
  float* q    = ws;                 // [784,128]
  float* ek   = ws + 100352;        // [784,128]
  float* vv   = ws + 200704;        // [784,128]
  float* W    = ws + 301056;        // [784,784]
  float* nump = ws + 915712;        // [8,784,128]
  float* denp = ws + 1718528;       // [8,784,128]

  posw_qkv<<<247, 256, 0, stream>>>(pu, pv, W, x, g1, b1n, wq, wk, wv, q, ek, vv);
  agg_gemm<<<dim3(13, 2, 8), 512, 0, stream>>>(W, ek, vv, nump, denp);
  epilogue_fused<<<98, 512, 0, stream>>>(q, nump, denp, wo, bo, x, g2, b2n,
                                         w1, b1f, w2, b2f, out);
}